// Round 9
// baseline (114.134 us; speedup 1.0000x reference)
//
#include <hip/hip_runtime.h>
#include <math.h>

#define D 20
#define NROWS 1000000
#define NTILES (NROWS / 16)            // 62500 16-row tiles
#define TPB 256
#define TILES_PER_BLK 16               // 16 tiles * 1280 B = 20 KB staged/block
#define NSB ((NTILES + TILES_PER_BLK - 1) / TILES_PER_BLK)   // 3907 blocks
#define NF4 (NROWS * D / 4)            // 5,000,000 float4s in X
#define F4_PER_SB (TILES_PER_BLK * 16 * D / 4)               // 1280 float4/superblock

typedef float  f32x4  __attribute__((ext_vector_type(4)));
typedef __bf16 bf16x8 __attribute__((ext_vector_type(8)));

// ws layout (all regions written before read every launch -> poison-safe):
//   [0, NSB*16)        : per-block partials (S, Sabs) doubles = 62512 B
//   [CNT_OFF, +4)      : arrival counter (zeroed by setup_kernel each launch)
//   [FRAG_OFF, +4096)  : 4 MFMA constant fragments, 64 lanes x 16B each
#define CNT_OFF 65536
#define FRAG_OFF (CNT_OFF + 256)

__device__ inline unsigned int pk2(float a, float b) {
  unsigned short la = __builtin_bit_cast(unsigned short, (__bf16)a);
  unsigned short lb = __builtin_bit_cast(unsigned short, (__bf16)b);
  return (unsigned int)la | ((unsigned int)lb << 16);
}

// ---------------------------------------------------------------------------
// Setup (1 block, once): fold layers + build MFMA constant fragments;
// also zeroes the arrival counter (kernel-completion release -> visible).
//   A[j][m] = sum_i W[i][j]*R[i][m];  c[m] = 1 + sum_i b[i]*R[i][m]
// Fragments (16x16x32 bf16: lane l holds k=(l>>4)*8+e):
//   B1t1/B1t2: A^T rows m=ii/16+ii, k=j; k==20 slot = c[m]
//   B2t1/B2t2: W cols n=ii/16+ii, SIGMA-permuted k-rows
//     sigma(G,e)= e<4 ? 4G+e : 16+4G+(e-4); slot sigma==20 = b[n]
//   (permutation makes GEMM1 acc regs feed GEMM2 A-frag with no cross-lane ops)
// ---------------------------------------------------------------------------
__global__ __launch_bounds__(512) void setup_kernel(
    const float* __restrict__ W, const float* __restrict__ b,
    const float* __restrict__ R, unsigned int* __restrict__ frags,
    unsigned int* __restrict__ counter) {
  __shared__ float A_s[D * D];
  __shared__ float c_s[D];
  const int t = threadIdx.x;
  if (t == 511) *counter = 0u;
  if (t < D * D) {
    int j = t / D, m = t % D;
    float s = 0.f;
#pragma unroll
    for (int i = 0; i < D; ++i) s = fmaf(W[i * D + j], R[i * D + m], s);
    A_s[j * D + m] = s;
  } else if (t < D * D + D) {
    int m = t - D * D;
    float s = 1.0f;
#pragma unroll
    for (int i = 0; i < D; ++i) s = fmaf(b[i], R[i * D + m], s);
    c_s[m] = s;
  }
  __syncthreads();
  if (t < 64) {
    const int G = t >> 4, ii = t & 15;
    uint4* out = (uint4*)frags;
    unsigned w[4];
    for (int wd = 0; wd < 4; ++wd) {            // B1t1: rows m = ii
      float v[2];
      for (int h = 0; h < 2; ++h) {
        int k = G * 8 + 2 * wd + h;
        v[h] = (k < D) ? A_s[k * D + ii] : (k == D ? c_s[ii] : 0.f);
      }
      w[wd] = pk2(v[0], v[1]);
    }
    out[t] = make_uint4(w[0], w[1], w[2], w[3]);
    for (int wd = 0; wd < 4; ++wd) {            // B1t2: rows m = 16+ii
      float v[2];
      for (int h = 0; h < 2; ++h) {
        int k = G * 8 + 2 * wd + h;
        int m = 16 + ii;
        v[h] = (m < D) ? ((k < D) ? A_s[k * D + m] : (k == D ? c_s[m] : 0.f)) : 0.f;
      }
      w[wd] = pk2(v[0], v[1]);
    }
    out[64 + t] = make_uint4(w[0], w[1], w[2], w[3]);
    for (int wd = 0; wd < 4; ++wd) {            // B2t1: cols n = ii
      float v[2];
      for (int h = 0; h < 2; ++h) {
        int e = 2 * wd + h;
        int sg = (e < 4) ? (4 * G + e) : (16 + 4 * G + (e - 4));
        v[h] = (sg < D) ? W[ii * D + sg] : (sg == D ? b[ii] : 0.f);
      }
      w[wd] = pk2(v[0], v[1]);
    }
    out[128 + t] = make_uint4(w[0], w[1], w[2], w[3]);
    for (int wd = 0; wd < 4; ++wd) {            // B2t2: cols n = 16+ii
      float v[2];
      for (int h = 0; h < 2; ++h) {
        int e = 2 * wd + h;
        int sg = (e < 4) ? (4 * G + e) : (16 + 4 * G + (e - 4));
        int n = 16 + ii;
        v[h] = (n < D) ? ((sg < D) ? W[n * D + sg] : (sg == D ? b[n] : 0.f)) : 0.f;
      }
      w[wd] = pk2(v[0], v[1]);
    }
    out[192 + t] = make_uint4(w[0], w[1], w[2], w[3]);
  }
}

// ---------------------------------------------------------------------------
// Main: one block = one 16-tile superblock (20 KB of X), R7 structure.
// Tail protocol (NO __threadfence -> NO buffer_wbl2): partials written with
// agent-scope atomic stores (LLC-visible), ordered by the release half of a
// scoped fetch_add; last-arriving block acquires (L2 inv) and reduces all
// partials in FIXED order (deterministic), then does the exact halving math.
// ---------------------------------------------------------------------------
__global__ __launch_bounds__(TPB) void main_kernel(
    const float* __restrict__ X, const unsigned int* __restrict__ frags,
    double* __restrict__ partial, unsigned int* __restrict__ counter,
    float* __restrict__ out) {
  __shared__ float4 xs4[F4_PER_SB + 2];   // 20 KB + 32 B const zones
  __shared__ double red[8];
  __shared__ int amLast;
  float* xs = (float*)xs4;
  const int t = threadIdx.x;
  const int s = blockIdx.x;

  // ---- stage: X fully coalesced (5 float4/thread), clamped at X end ----
  const float4* X4 = (const float4*)X;
#pragma unroll
  for (int j = 0; j < 5; ++j) {
    int gi = s * F4_PER_SB + j * TPB + t;
    gi = (gi < NF4) ? gi : (NF4 - 1);            // tail: garbage, guarded below
    xs4[j * TPB + t] = X4[gi];
  }
  if (t < 8) xs[4 * F4_PER_SB + t] = (t == 0) ? 1.0f : 0.0f;  // {1,0,0,0},{0,0,0,0}

  // frag loads overlap the staging latency
  const int lane = t & 63;
  const int G = lane >> 4, ii = lane & 15;
  const int wid = t >> 6;
  const uint4* fr = (const uint4*)frags;
  const bf16x8 B1t1 = __builtin_bit_cast(bf16x8, fr[lane]);
  const bf16x8 B1t2 = __builtin_bit_cast(bf16x8, fr[64 + lane]);
  const bf16x8 B2t1 = __builtin_bit_cast(bf16x8, fr[128 + lane]);
  const bf16x8 B2t2 = __builtin_bit_cast(bf16x8, fr[192 + lane]);
  __syncthreads();

  // ---- compute: 4 tiles/wave; zero-region bases -> select-free frag build ----
  // lane's X-frag k-slots: G*8+e. G<2: all real; G==2: k=16..19 real then
  // {1,0,0,0} (k==20 -> 1.0 feeds the c-slot); G==3: all zero.
  float* zC = xs + 4 * F4_PER_SB;                // {1,0,0,0}
  float* zZ = zC + 4;                            // {0,0,0,0}
  const float* caBase; int caStr;
  const float* cbBase; int cbStr;
  if (G < 2)       { caBase = xs + ii * D + G * 8; caStr = 16 * D;
                     cbBase = caBase + 4;          cbStr = 16 * D; }
  else if (G == 2) { caBase = xs + ii * D + 16;    caStr = 16 * D;
                     cbBase = zC;                  cbStr = 0; }
  else             { caBase = zZ;                  caStr = 0;
                     cbBase = zZ;                  cbStr = 0; }

  double s64 = 0.0, sa64 = 0.0;
#pragma unroll
  for (int k = 0; k < 4; ++k) {
    const int wt = wid * 4 + k;
    if (s * TILES_PER_BLK + wt < NTILES) {       // wave-uniform guard (tail)
      const float4 ca = *(const float4*)(caBase + wt * caStr);
      const float4 cb = *(const float4*)(cbBase + wt * cbStr);
      bf16x8 xf;
      xf[0] = (__bf16)ca.x; xf[1] = (__bf16)ca.y;
      xf[2] = (__bf16)ca.z; xf[3] = (__bf16)ca.w;
      xf[4] = (__bf16)cb.x; xf[5] = (__bf16)cb.y;
      xf[6] = (__bf16)cb.z; xf[7] = (__bf16)cb.w;

      const f32x4 zz = {0.f, 0.f, 0.f, 0.f};
      f32x4 a1 = __builtin_amdgcn_mfma_f32_16x16x32_bf16(B1t1, xf, zz, 0, 0, 0);
      f32x4 a2 = __builtin_amdgcn_mfma_f32_16x16x32_bf16(B1t2, xf, zz, 0, 0, 0);
#pragma unroll
      for (int q = 0; q < 4; ++q) {
        a1[q] = fmaxf(a1[q], 0.f);
        a2[q] = fmaxf(a2[q], 0.f);
      }
      const float hj = (G == 1) ? 1.0f : a2[0];  // m=20 slot carries 1.0 (b-row)
      bf16x8 x2f;
      x2f[0] = (__bf16)a1[0]; x2f[1] = (__bf16)a1[1];
      x2f[2] = (__bf16)a1[2]; x2f[3] = (__bf16)a1[3];
      x2f[4] = (__bf16)hj;    x2f[5] = (__bf16)a2[1];
      x2f[6] = (__bf16)a2[2]; x2f[7] = (__bf16)a2[3];

      f32x4 z1 = __builtin_amdgcn_mfma_f32_16x16x32_bf16(x2f, B2t1, zz, 0, 0, 0);
      f32x4 z2 = __builtin_amdgcn_mfma_f32_16x16x32_bf16(x2f, B2t2, zz, 0, 0, 0);

      const float s8 = ((z1[0] + z1[1]) + (z1[2] + z1[3])) +
                       ((z2[0] + z2[1]) + (z2[2] + z2[3]));
      const float sa8 =
          ((fabsf(z1[0]) + fabsf(z1[1])) + (fabsf(z1[2]) + fabsf(z1[3]))) +
          ((fabsf(z2[0]) + fabsf(z2[1])) + (fabsf(z2[2]) + fabsf(z2[3])));
      s64 += (double)s8;
      sa64 += (double)sa8;
    }
  }

  // ---- block reduce: wave64 shfl (f64) -> 4-wave LDS -> one pair/block ----
#pragma unroll
  for (int off = 32; off > 0; off >>= 1) {
    s64 += __shfl_down(s64, off, 64);
    sa64 += __shfl_down(sa64, off, 64);
  }
  if ((t & 63) == 0) { red[wid * 2] = s64; red[wid * 2 + 1] = sa64; }
  __syncthreads();
  if (t == 0) {
    // agent-scope (LLC-visible) stores -- no L2 writeback fence needed
    __hip_atomic_store(&partial[2 * s],     red[0] + red[2] + red[4] + red[6],
                       __ATOMIC_RELAXED, __HIP_MEMORY_SCOPE_AGENT);
    __hip_atomic_store(&partial[2 * s + 1], red[1] + red[3] + red[5] + red[7],
                       __ATOMIC_RELAXED, __HIP_MEMORY_SCOPE_AGENT);
    // release orders the two stores above; acquire invalidates L2 for winner
    unsigned int old = __hip_atomic_fetch_add(counter, 1u, __ATOMIC_ACQ_REL,
                                              __HIP_MEMORY_SCOPE_AGENT);
    amLast = (old == NSB - 1);
  }
  __syncthreads();

  // ---- last-arriving block: deterministic fixed-order final reduce ----
  if (amLast) {
    double s = 0.0, sa = 0.0;
    for (int i = t; i < NSB; i += TPB) {
      s += __hip_atomic_load(&partial[2 * i], __ATOMIC_RELAXED,
                             __HIP_MEMORY_SCOPE_AGENT);
      sa += __hip_atomic_load(&partial[2 * i + 1], __ATOMIC_RELAXED,
                              __HIP_MEMORY_SCOPE_AGENT);
    }
#pragma unroll
    for (int off = 32; off > 0; off >>= 1) {
      s += __shfl_down(s, off, 64);
      sa += __shfl_down(sa, off, 64);
    }
    if ((t & 63) == 0) { red[wid * 2] = s; red[wid * 2 + 1] = sa; }
    __syncthreads();
    if (t == 0) {
      double S  = red[0] + red[2] + red[4] + red[6];
      double SA = red[1] + red[3] + red[5] + red[7];
      int k = 0;
      double tt = SA;
      while (tt > 1.0 && k < 4096) { tt *= 0.5; ++k; }  // exact: /2 per ref iter
      out[0] = (float)ldexp(S, -k);
    }
  }
}

extern "C" void kernel_launch(void* const* d_in, const int* in_sizes, int n_in,
                              void* d_out, int out_size, void* d_ws, size_t ws_size,
                              hipStream_t stream) {
  const float* X = (const float*)d_in[0];
  const float* W = (const float*)d_in[1];
  const float* b = (const float*)d_in[2];
  const float* R = (const float*)d_in[3];
  char* ws = (char*)d_ws;
  double* partial = (double*)ws;
  unsigned int* counter = (unsigned int*)(ws + CNT_OFF);
  unsigned int* frags = (unsigned int*)(ws + FRAG_OFF);

  setup_kernel<<<1, 512, 0, stream>>>(W, b, R, frags, counter);
  main_kernel<<<NSB, TPB, 0, stream>>>(X, frags, partial, counter,
                                       (float*)d_out);
}

// Round 10
// 67.141 us; speedup vs baseline: 1.6999x; 1.6999x over previous
//
#include <hip/hip_runtime.h>
#include <math.h>

#define D 20
#define NROWS 1000000
#define NTILES (NROWS / 16)            // 62500 16-row tiles
#define TPB 256
#define TILES_PER_BLK 16               // 16 tiles * 1280 B = 20 KB staged/block
#define NSB ((NTILES + TILES_PER_BLK - 1) / TILES_PER_BLK)   // 3907 blocks
#define NF4 (NROWS * D / 4)            // 5,000,000 float4s in X
#define F4_PER_SB (TILES_PER_BLK * 16 * D / 4)               // 1280 float4/superblock

typedef float  f32x4  __attribute__((ext_vector_type(4)));
typedef __bf16 bf16x8 __attribute__((ext_vector_type(8)));

// ws layout (all regions written before read every launch -> poison-safe):
//   [0, NSB*16)        : per-block partials (S, Sabs) doubles = 62512 B
//   [CNT_OFF, +4)      : arrival counter (zeroed by setup_kernel each launch)
//   [FRAG_OFF, +4096)  : 4 MFMA constant fragments, 64 lanes x 16B each
#define CNT_OFF 65536
#define FRAG_OFF (CNT_OFF + 256)

__device__ inline unsigned int pk2(float a, float b) {
  unsigned short la = __builtin_bit_cast(unsigned short, (__bf16)a);
  unsigned short lb = __builtin_bit_cast(unsigned short, (__bf16)b);
  return (unsigned int)la | ((unsigned int)lb << 16);
}

// ---------------------------------------------------------------------------
// Setup (1 block, once): fold layers + build MFMA constant fragments;
// zeroes the arrival counter via agent-scope atomic store (LLC-visible).
//   A[j][m] = sum_i W[i][j]*R[i][m];  c[m] = 1 + sum_i b[i]*R[i][m]
// Fragments (16x16x32 bf16: lane l holds k=(l>>4)*8+e):
//   B1t1/B1t2: A^T rows m=ii/16+ii, k=j; k==20 slot = c[m]
//   B2t1/B2t2: W cols n=ii/16+ii, SIGMA-permuted k-rows
//     sigma(G,e)= e<4 ? 4G+e : 16+4G+(e-4); slot sigma==20 = b[n]
//   (permutation makes GEMM1 acc regs feed GEMM2 A-frag with no cross-lane ops)
// ---------------------------------------------------------------------------
__global__ __launch_bounds__(512) void setup_kernel(
    const float* __restrict__ W, const float* __restrict__ b,
    const float* __restrict__ R, unsigned int* __restrict__ frags,
    unsigned int* __restrict__ counter) {
  __shared__ float A_s[D * D];
  __shared__ float c_s[D];
  const int t = threadIdx.x;
  if (t == 511)
    __hip_atomic_store(counter, 0u, __ATOMIC_RELAXED, __HIP_MEMORY_SCOPE_AGENT);
  if (t < D * D) {
    int j = t / D, m = t % D;
    float s = 0.f;
#pragma unroll
    for (int i = 0; i < D; ++i) s = fmaf(W[i * D + j], R[i * D + m], s);
    A_s[j * D + m] = s;
  } else if (t < D * D + D) {
    int m = t - D * D;
    float s = 1.0f;
#pragma unroll
    for (int i = 0; i < D; ++i) s = fmaf(b[i], R[i * D + m], s);
    c_s[m] = s;
  }
  __syncthreads();
  if (t < 64) {
    const int G = t >> 4, ii = t & 15;
    uint4* out = (uint4*)frags;
    unsigned w[4];
    for (int wd = 0; wd < 4; ++wd) {            // B1t1: rows m = ii
      float v[2];
      for (int h = 0; h < 2; ++h) {
        int k = G * 8 + 2 * wd + h;
        v[h] = (k < D) ? A_s[k * D + ii] : (k == D ? c_s[ii] : 0.f);
      }
      w[wd] = pk2(v[0], v[1]);
    }
    out[t] = make_uint4(w[0], w[1], w[2], w[3]);
    for (int wd = 0; wd < 4; ++wd) {            // B1t2: rows m = 16+ii
      float v[2];
      for (int h = 0; h < 2; ++h) {
        int k = G * 8 + 2 * wd + h;
        int m = 16 + ii;
        v[h] = (m < D) ? ((k < D) ? A_s[k * D + m] : (k == D ? c_s[m] : 0.f)) : 0.f;
      }
      w[wd] = pk2(v[0], v[1]);
    }
    out[64 + t] = make_uint4(w[0], w[1], w[2], w[3]);
    for (int wd = 0; wd < 4; ++wd) {            // B2t1: cols n = ii
      float v[2];
      for (int h = 0; h < 2; ++h) {
        int e = 2 * wd + h;
        int sg = (e < 4) ? (4 * G + e) : (16 + 4 * G + (e - 4));
        v[h] = (sg < D) ? W[ii * D + sg] : (sg == D ? b[ii] : 0.f);
      }
      w[wd] = pk2(v[0], v[1]);
    }
    out[128 + t] = make_uint4(w[0], w[1], w[2], w[3]);
    for (int wd = 0; wd < 4; ++wd) {            // B2t2: cols n = 16+ii
      float v[2];
      for (int h = 0; h < 2; ++h) {
        int e = 2 * wd + h;
        int sg = (e < 4) ? (4 * G + e) : (16 + 4 * G + (e - 4));
        int n = 16 + ii;
        v[h] = (n < D) ? ((sg < D) ? W[n * D + sg] : (sg == D ? b[n] : 0.f)) : 0.f;
      }
      w[wd] = pk2(v[0], v[1]);
    }
    out[192 + t] = make_uint4(w[0], w[1], w[2], w[3]);
  }
}

// ---------------------------------------------------------------------------
// Main: R7 structure verbatim. Tail with ZERO cache-maintenance instructions:
//   - partials: agent-scope RELAXED atomic stores (write-through -> LLC; no
//     dirty L2 lines => no wbl2 needed, ever)
//   - ordering: raw s_waitcnt vmcnt(0) (stores complete at coherence point),
//     then RELAXED fetch_add (no acquire => no buffer_inv)
//   - winner: agent-scope RELAXED atomic loads (L2-bypass -> no staleness),
//     fixed-order reduce (deterministic), exact halving math, write out.
// ---------------------------------------------------------------------------
__global__ __launch_bounds__(TPB) void main_kernel(
    const float* __restrict__ X, const unsigned int* __restrict__ frags,
    double* __restrict__ partial, unsigned int* __restrict__ counter,
    float* __restrict__ out) {
  __shared__ float4 xs4[F4_PER_SB + 2];   // 20 KB + 32 B const zones
  __shared__ double red[8];
  __shared__ int amLast;
  float* xs = (float*)xs4;
  const int t = threadIdx.x;
  const int s = blockIdx.x;

  // ---- stage: X fully coalesced (5 float4/thread), clamped at X end ----
  const float4* X4 = (const float4*)X;
#pragma unroll
  for (int j = 0; j < 5; ++j) {
    int gi = s * F4_PER_SB + j * TPB + t;
    gi = (gi < NF4) ? gi : (NF4 - 1);            // tail: garbage, guarded below
    xs4[j * TPB + t] = X4[gi];
  }
  if (t < 8) xs[4 * F4_PER_SB + t] = (t == 0) ? 1.0f : 0.0f;  // {1,0,0,0},{0,...}

  // frag loads overlap the staging latency
  const int lane = t & 63;
  const int G = lane >> 4, ii = lane & 15;
  const int wid = t >> 6;
  const uint4* fr = (const uint4*)frags;
  const bf16x8 B1t1 = __builtin_bit_cast(bf16x8, fr[lane]);
  const bf16x8 B1t2 = __builtin_bit_cast(bf16x8, fr[64 + lane]);
  const bf16x8 B2t1 = __builtin_bit_cast(bf16x8, fr[128 + lane]);
  const bf16x8 B2t2 = __builtin_bit_cast(bf16x8, fr[192 + lane]);
  __syncthreads();

  // ---- compute: 4 tiles/wave; zero-region bases -> select-free frag build ----
  // lane's X-frag k-slots: G*8+e. G<2: all real; G==2: k=16..19 real then
  // {1,0,0,0} (k==20 -> 1.0 feeds the c-slot); G==3: all zero.
  float* zC = xs + 4 * F4_PER_SB;                // {1,0,0,0}
  float* zZ = zC + 4;                            // {0,0,0,0}
  const float* caBase; int caStr;
  const float* cbBase; int cbStr;
  if (G < 2)       { caBase = xs + ii * D + G * 8; caStr = 16 * D;
                     cbBase = caBase + 4;          cbStr = 16 * D; }
  else if (G == 2) { caBase = xs + ii * D + 16;    caStr = 16 * D;
                     cbBase = zC;                  cbStr = 0; }
  else             { caBase = zZ;                  caStr = 0;
                     cbBase = zZ;                  cbStr = 0; }

  double s64 = 0.0, sa64 = 0.0;
#pragma unroll
  for (int k = 0; k < 4; ++k) {
    const int wt = wid * 4 + k;
    if (s * TILES_PER_BLK + wt < NTILES) {       // wave-uniform guard (tail)
      const float4 ca = *(const float4*)(caBase + wt * caStr);
      const float4 cb = *(const float4*)(cbBase + wt * cbStr);
      bf16x8 xf;
      xf[0] = (__bf16)ca.x; xf[1] = (__bf16)ca.y;
      xf[2] = (__bf16)ca.z; xf[3] = (__bf16)ca.w;
      xf[4] = (__bf16)cb.x; xf[5] = (__bf16)cb.y;
      xf[6] = (__bf16)cb.z; xf[7] = (__bf16)cb.w;

      const f32x4 zz = {0.f, 0.f, 0.f, 0.f};
      f32x4 a1 = __builtin_amdgcn_mfma_f32_16x16x32_bf16(B1t1, xf, zz, 0, 0, 0);
      f32x4 a2 = __builtin_amdgcn_mfma_f32_16x16x32_bf16(B1t2, xf, zz, 0, 0, 0);
#pragma unroll
      for (int q = 0; q < 4; ++q) {
        a1[q] = fmaxf(a1[q], 0.f);
        a2[q] = fmaxf(a2[q], 0.f);
      }
      const float hj = (G == 1) ? 1.0f : a2[0];  // m=20 slot carries 1.0 (b-row)
      bf16x8 x2f;
      x2f[0] = (__bf16)a1[0]; x2f[1] = (__bf16)a1[1];
      x2f[2] = (__bf16)a1[2]; x2f[3] = (__bf16)a1[3];
      x2f[4] = (__bf16)hj;    x2f[5] = (__bf16)a2[1];
      x2f[6] = (__bf16)a2[2]; x2f[7] = (__bf16)a2[3];

      f32x4 z1 = __builtin_amdgcn_mfma_f32_16x16x32_bf16(x2f, B2t1, zz, 0, 0, 0);
      f32x4 z2 = __builtin_amdgcn_mfma_f32_16x16x32_bf16(x2f, B2t2, zz, 0, 0, 0);

      const float s8 = ((z1[0] + z1[1]) + (z1[2] + z1[3])) +
                       ((z2[0] + z2[1]) + (z2[2] + z2[3]));
      const float sa8 =
          ((fabsf(z1[0]) + fabsf(z1[1])) + (fabsf(z1[2]) + fabsf(z1[3]))) +
          ((fabsf(z2[0]) + fabsf(z2[1])) + (fabsf(z2[2]) + fabsf(z2[3])));
      s64 += (double)s8;
      sa64 += (double)sa8;
    }
  }

  // ---- block reduce: wave64 shfl (f64) -> 4-wave LDS -> one pair/block ----
#pragma unroll
  for (int off = 32; off > 0; off >>= 1) {
    s64 += __shfl_down(s64, off, 64);
    sa64 += __shfl_down(sa64, off, 64);
  }
  if ((t & 63) == 0) { red[wid * 2] = s64; red[wid * 2 + 1] = sa64; }
  __syncthreads();
  if (t == 0) {
    // write-through stores (no L2 dirty lines; visible at LLC once vmcnt==0)
    __hip_atomic_store(&partial[2 * s],     red[0] + red[2] + red[4] + red[6],
                       __ATOMIC_RELAXED, __HIP_MEMORY_SCOPE_AGENT);
    __hip_atomic_store(&partial[2 * s + 1], red[1] + red[3] + red[5] + red[7],
                       __ATOMIC_RELAXED, __HIP_MEMORY_SCOPE_AGENT);
    // order: stores reach coherence point before the counter bump; NO acquire,
    // NO release -> no buffer_inv / buffer_wbl2 anywhere in this kernel.
    asm volatile("s_waitcnt vmcnt(0)" ::: "memory");
    unsigned int old = __hip_atomic_fetch_add(counter, 1u, __ATOMIC_RELAXED,
                                              __HIP_MEMORY_SCOPE_AGENT);
    amLast = (old == NSB - 1);
  }
  __syncthreads();

  // ---- last-arriving block: deterministic fixed-order final reduce ----
  if (amLast) {
    double s = 0.0, sa = 0.0;
    for (int i = t; i < NSB; i += TPB) {
      s += __hip_atomic_load(&partial[2 * i], __ATOMIC_RELAXED,
                             __HIP_MEMORY_SCOPE_AGENT);
      sa += __hip_atomic_load(&partial[2 * i + 1], __ATOMIC_RELAXED,
                              __HIP_MEMORY_SCOPE_AGENT);
    }
#pragma unroll
    for (int off = 32; off > 0; off >>= 1) {
      s += __shfl_down(s, off, 64);
      sa += __shfl_down(sa, off, 64);
    }
    if ((t & 63) == 0) { red[wid * 2] = s; red[wid * 2 + 1] = sa; }
    __syncthreads();
    if (t == 0) {
      double S  = red[0] + red[2] + red[4] + red[6];
      double SA = red[1] + red[3] + red[5] + red[7];
      int k = 0;
      double tt = SA;
      while (tt > 1.0 && k < 4096) { tt *= 0.5; ++k; }  // exact: /2 per ref iter
      out[0] = (float)ldexp(S, -k);
    }
  }
}

extern "C" void kernel_launch(void* const* d_in, const int* in_sizes, int n_in,
                              void* d_out, int out_size, void* d_ws, size_t ws_size,
                              hipStream_t stream) {
  const float* X = (const float*)d_in[0];
  const float* W = (const float*)d_in[1];
  const float* b = (const float*)d_in[2];
  const float* R = (const float*)d_in[3];
  char* ws = (char*)d_ws;
  double* partial = (double*)ws;
  unsigned int* counter = (unsigned int*)(ws + CNT_OFF);
  unsigned int* frags = (unsigned int*)(ws + FRAG_OFF);

  setup_kernel<<<1, 512, 0, stream>>>(W, b, R, frags, counter);
  main_kernel<<<NSB, TPB, 0, stream>>>(X, frags, partial, counter,
                                       (float*)d_out);
}

// Round 11
// 32.255 us; speedup vs baseline: 3.5385x; 2.0816x over previous
//
#include <hip/hip_runtime.h>
#include <math.h>

#define D 20
#define NROWS 1000000
#define NTILES (NROWS / 16)            // 62500 16-row tiles
#define TPB 256
#define TILES_PER_BLK 16               // superblock = 16 tiles = 20 KB
#define NSB ((NTILES + TILES_PER_BLK - 1) / TILES_PER_BLK)   // 3907 superblocks
#define NBLK 1024                      // persistent blocks, grid-stride over SBs
#define NF4 (NROWS * D / 4)            // 5,000,000 float4s in X
#define F4_PER_SB (TILES_PER_BLK * 16 * D / 4)               // 1280 float4/SB

typedef float  f32x4  __attribute__((ext_vector_type(4)));
typedef __bf16 bf16x8 __attribute__((ext_vector_type(8)));

#define AS1 __attribute__((address_space(1)))
#define AS3 __attribute__((address_space(3)))

// ws layout (all regions written before read every launch -> poison-safe):
//   [0, NBLK*16)       : per-block partials (S, Sabs) doubles
//   [FRAG_OFF, +4096)  : 4 MFMA constant fragments, 64 lanes x 16B each
#define FRAG_OFF (NBLK * 16)

__device__ inline unsigned int pk2(float a, float b) {
  unsigned short la = __builtin_bit_cast(unsigned short, (__bf16)a);
  unsigned short lb = __builtin_bit_cast(unsigned short, (__bf16)b);
  return (unsigned int)la | ((unsigned int)lb << 16);
}

// ---------------------------------------------------------------------------
// Setup (1 block, once): fold layers + build MFMA constant fragments.
//   A[j][m] = sum_i W[i][j]*R[i][m];  c[m] = 1 + sum_i b[i]*R[i][m]
// Fragments (16x16x32 bf16: lane l holds k=(l>>4)*8+e):
//   B1t1/B1t2: A^T rows m=ii/16+ii, k=j; k==20 slot = c[m]
//   B2t1/B2t2: W cols n=ii/16+ii, SIGMA-permuted k-rows
//     sigma(G,e)= e<4 ? 4G+e : 16+4G+(e-4); slot sigma==20 = b[n]
//   (permutation makes GEMM1 acc regs feed GEMM2 A-frag with no cross-lane ops)
// ---------------------------------------------------------------------------
__global__ __launch_bounds__(512) void setup_kernel(
    const float* __restrict__ W, const float* __restrict__ b,
    const float* __restrict__ R, unsigned int* __restrict__ frags) {
  __shared__ float A_s[D * D];
  __shared__ float c_s[D];
  const int t = threadIdx.x;
  if (t < D * D) {
    int j = t / D, m = t % D;
    float s = 0.f;
#pragma unroll
    for (int i = 0; i < D; ++i) s = fmaf(W[i * D + j], R[i * D + m], s);
    A_s[j * D + m] = s;
  } else if (t < D * D + D) {
    int m = t - D * D;
    float s = 1.0f;
#pragma unroll
    for (int i = 0; i < D; ++i) s = fmaf(b[i], R[i * D + m], s);
    c_s[m] = s;
  }
  __syncthreads();
  if (t < 64) {
    const int G = t >> 4, ii = t & 15;
    uint4* out = (uint4*)frags;
    unsigned w[4];
    for (int wd = 0; wd < 4; ++wd) {            // B1t1: rows m = ii
      float v[2];
      for (int h = 0; h < 2; ++h) {
        int k = G * 8 + 2 * wd + h;
        v[h] = (k < D) ? A_s[k * D + ii] : (k == D ? c_s[ii] : 0.f);
      }
      w[wd] = pk2(v[0], v[1]);
    }
    out[t] = make_uint4(w[0], w[1], w[2], w[3]);
    for (int wd = 0; wd < 4; ++wd) {            // B1t2: rows m = 16+ii
      float v[2];
      for (int h = 0; h < 2; ++h) {
        int k = G * 8 + 2 * wd + h;
        int m = 16 + ii;
        v[h] = (m < D) ? ((k < D) ? A_s[k * D + m] : (k == D ? c_s[m] : 0.f)) : 0.f;
      }
      w[wd] = pk2(v[0], v[1]);
    }
    out[64 + t] = make_uint4(w[0], w[1], w[2], w[3]);
    for (int wd = 0; wd < 4; ++wd) {            // B2t1: cols n = ii
      float v[2];
      for (int h = 0; h < 2; ++h) {
        int e = 2 * wd + h;
        int sg = (e < 4) ? (4 * G + e) : (16 + 4 * G + (e - 4));
        v[h] = (sg < D) ? W[ii * D + sg] : (sg == D ? b[ii] : 0.f);
      }
      w[wd] = pk2(v[0], v[1]);
    }
    out[128 + t] = make_uint4(w[0], w[1], w[2], w[3]);
    for (int wd = 0; wd < 4; ++wd) {            // B2t2: cols n = 16+ii
      float v[2];
      for (int h = 0; h < 2; ++h) {
        int e = 2 * wd + h;
        int sg = (e < 4) ? (4 * G + e) : (16 + 4 * G + (e - 4));
        int n = 16 + ii;
        v[h] = (n < D) ? ((sg < D) ? W[ii * 0 + n * D + sg] : (sg == D ? b[n] : 0.f)) : 0.f;
      }
      w[wd] = pk2(v[0], v[1]);
    }
    out[192 + t] = make_uint4(w[0], w[1], w[2], w[3]);
  }
}

// ---------------------------------------------------------------------------
// Main: 1024 persistent blocks, grid-stride over superblocks. Double-buffered
// LDS staging via global_load_lds (width=16, no VGPR roundtrip). Counted
// s_waitcnt vmcnt(5) + RAW s_barrier (never __syncthreads -> no vmcnt(0)
// drain): next-SB loads stay in flight across the barrier and land under
// the current SB's compute. 2 raw barriers per SB iteration.
// ---------------------------------------------------------------------------
__global__ __launch_bounds__(TPB) void main_kernel(
    const float* __restrict__ X, const unsigned int* __restrict__ frags,
    double* __restrict__ partial) {
  __shared__ float4 xs4[2 * F4_PER_SB + 2];   // 2 x 20 KB bufs + 32 B const zones
  float* xs = (float*)xs4;
  const int t = threadIdx.x;
  const int lane = t & 63;
  const int G = lane >> 4, ii = lane & 15;
  const int wid = t >> 6;
  const float4* X4 = (const float4*)X;

  // const zones {1,0,0,0} / {0,0,0,0} after both buffers
  if (t < 8) xs[8 * F4_PER_SB + t] = (t == 0) ? 1.0f : 0.0f;

  // frag loads (global, L2-hot after setup)
  const uint4* fr = (const uint4*)frags;
  const bf16x8 B1t1 = __builtin_bit_cast(bf16x8, fr[lane]);
  const bf16x8 B1t2 = __builtin_bit_cast(bf16x8, fr[64 + lane]);
  const bf16x8 B2t1 = __builtin_bit_cast(bf16x8, fr[128 + lane]);
  const bf16x8 B2t2 = __builtin_bit_cast(bf16x8, fr[192 + lane]);

  // async stage of one superblock into buffer bsel (5 x 16B per lane, DMA)
#define STAGE(bsel, sb)                                                        \
  do {                                                                         \
    _Pragma("unroll")                                                          \
    for (int j = 0; j < 5; ++j) {                                              \
      int f4i = (sb) * F4_PER_SB + j * TPB + t;                                \
      f4i = (f4i < NF4) ? f4i : (NF4 - 1);     /* clamp: garbage, guarded */   \
      __builtin_amdgcn_global_load_lds(                                        \
          (AS1 const void*)(X4 + f4i),                                         \
          (AS3 void*)(xs4 + (bsel) * F4_PER_SB + j * (TPB / 4) * 4 + wid * 64),\
          16, 0, 0);                                                           \
    }                                                                          \
  } while (0)

  int sb = blockIdx.x;
  STAGE(0, sb);
  asm volatile("s_waitcnt lgkmcnt(0)" ::: "memory");  // zone writes visible
  double s64 = 0.0, sa64 = 0.0;
  int cur = 0;

  for (; sb < NSB; sb += NBLK) {
    const int nxt = sb + NBLK;
    const bool has = (nxt < NSB);               // wave-uniform
    if (has) {
      STAGE(cur ^ 1, nxt);
      asm volatile("s_waitcnt vmcnt(5)" ::: "memory");  // buf[cur] landed
    } else {
      asm volatile("s_waitcnt vmcnt(0)" ::: "memory");
    }
    __builtin_amdgcn_sched_barrier(0);
    __builtin_amdgcn_s_barrier();               // raw: no vmcnt(0) auto-drain

    // ---- compute 4 tiles/wave from buf[cur]; zero-region select-free ----
    float* xsb = xs + cur * (F4_PER_SB * 4);
    float* zC = xs + 8 * F4_PER_SB;             // {1,0,0,0}
    float* zZ = zC + 4;                         // {0,0,0,0}
    const float* caBase; int caStr;
    const float* cbBase; int cbStr;
    if (G < 2)       { caBase = xsb + ii * D + G * 8; caStr = 16 * D;
                       cbBase = caBase + 4;           cbStr = 16 * D; }
    else if (G == 2) { caBase = xsb + ii * D + 16;    caStr = 16 * D;
                       cbBase = zC;                   cbStr = 0; }
    else             { caBase = zZ;                   caStr = 0;
                       cbBase = zZ;                   cbStr = 0; }

#pragma unroll
    for (int k = 0; k < 4; ++k) {
      const int wt = wid * 4 + k;
      if (sb * TILES_PER_BLK + wt < NTILES) {   // wave-uniform guard (tail)
        const float4 ca = *(const float4*)(caBase + wt * caStr);
        const float4 cb = *(const float4*)(cbBase + wt * cbStr);
        bf16x8 xf;
        xf[0] = (__bf16)ca.x; xf[1] = (__bf16)ca.y;
        xf[2] = (__bf16)ca.z; xf[3] = (__bf16)ca.w;
        xf[4] = (__bf16)cb.x; xf[5] = (__bf16)cb.y;
        xf[6] = (__bf16)cb.z; xf[7] = (__bf16)cb.w;

        const f32x4 zz = {0.f, 0.f, 0.f, 0.f};
        f32x4 a1 = __builtin_amdgcn_mfma_f32_16x16x32_bf16(B1t1, xf, zz, 0, 0, 0);
        f32x4 a2 = __builtin_amdgcn_mfma_f32_16x16x32_bf16(B1t2, xf, zz, 0, 0, 0);
#pragma unroll
        for (int q = 0; q < 4; ++q) {
          a1[q] = fmaxf(a1[q], 0.f);
          a2[q] = fmaxf(a2[q], 0.f);
        }
        const float hj = (G == 1) ? 1.0f : a2[0];  // m=20 slot = 1.0 (b-row)
        bf16x8 x2f;
        x2f[0] = (__bf16)a1[0]; x2f[1] = (__bf16)a1[1];
        x2f[2] = (__bf16)a1[2]; x2f[3] = (__bf16)a1[3];
        x2f[4] = (__bf16)hj;    x2f[5] = (__bf16)a2[1];
        x2f[6] = (__bf16)a2[2]; x2f[7] = (__bf16)a2[3];

        f32x4 z1 = __builtin_amdgcn_mfma_f32_16x16x32_bf16(x2f, B2t1, zz, 0, 0, 0);
        f32x4 z2 = __builtin_amdgcn_mfma_f32_16x16x32_bf16(x2f, B2t2, zz, 0, 0, 0);

        const float s8 = ((z1[0] + z1[1]) + (z1[2] + z1[3])) +
                         ((z2[0] + z2[1]) + (z2[2] + z2[3]));
        const float sa8 =
            ((fabsf(z1[0]) + fabsf(z1[1])) + (fabsf(z1[2]) + fabsf(z1[3]))) +
            ((fabsf(z2[0]) + fabsf(z2[1])) + (fabsf(z2[2]) + fabsf(z2[3])));
        s64 += (double)s8;
        sa64 += (double)sa8;
      }
    }
    __builtin_amdgcn_s_barrier();               // all waves done reading buf[cur]
    cur ^= 1;
  }

  // ---- block reduce: wave64 shfl (f64) -> 4-wave LDS -> one pair/block ----
#pragma unroll
  for (int off = 32; off > 0; off >>= 1) {
    s64 += __shfl_down(s64, off, 64);
    sa64 += __shfl_down(sa64, off, 64);
  }
  __shared__ double red[8];
  if ((t & 63) == 0) { red[wid * 2] = s64; red[wid * 2 + 1] = sa64; }
  __syncthreads();
  if (t == 0) {
    partial[2 * blockIdx.x]     = red[0] + red[2] + red[4] + red[6];
    partial[2 * blockIdx.x + 1] = red[1] + red[3] + red[5] + red[7];
  }
}

// ---------------------------------------------------------------------------
// Finalize: reduce NBLK partial pairs in fixed order; halving loop is exact
// scalar math: k = #halvings until abs-sum <= 1; out = ldexp(S, -k).
// ---------------------------------------------------------------------------
__global__ __launch_bounds__(256) void final_kernel(
    const double* __restrict__ partial, float* __restrict__ out) {
  double s = 0.0, sa = 0.0;
  for (int i = threadIdx.x; i < NBLK; i += 256) {
    s += partial[2 * i];
    sa += partial[2 * i + 1];
  }
#pragma unroll
  for (int off = 32; off > 0; off >>= 1) {
    s += __shfl_down(s, off, 64);
    sa += __shfl_down(sa, off, 64);
  }
  __shared__ double red[8];
  int wid = threadIdx.x >> 6;
  if ((threadIdx.x & 63) == 0) { red[wid * 2] = s; red[wid * 2 + 1] = sa; }
  __syncthreads();
  if (threadIdx.x == 0) {
    double S  = red[0] + red[2] + red[4] + red[6];
    double SA = red[1] + red[3] + red[5] + red[7];
    int k = 0;
    double t = SA;
    while (t > 1.0 && k < 4096) { t *= 0.5; ++k; }  // exact: /2 per ref iter
    out[0] = (float)ldexp(S, -k);
  }
}

extern "C" void kernel_launch(void* const* d_in, const int* in_sizes, int n_in,
                              void* d_out, int out_size, void* d_ws, size_t ws_size,
                              hipStream_t stream) {
  const float* X = (const float*)d_in[0];
  const float* W = (const float*)d_in[1];
  const float* b = (const float*)d_in[2];
  const float* R = (const float*)d_in[3];
  char* ws = (char*)d_ws;
  double* partial = (double*)ws;
  unsigned int* frags = (unsigned int*)(ws + FRAG_OFF);

  setup_kernel<<<1, 512, 0, stream>>>(W, b, R, frags);
  main_kernel<<<NBLK, TPB, 0, stream>>>(X, frags, partial);
  final_kernel<<<1, 256, 0, stream>>>(partial, (float*)d_out);
}